// Round 1
// baseline (312.655 us; speedup 1.0000x reference)
//
#include <hip/hip_runtime.h>
#include <math.h>

#define B_ 512
#define N_ 120
#define D_ 64
#define ROWS (B_ * N_)  // 61440

// full 64-lane butterfly sum; result on all lanes
__device__ __forceinline__ float wsum(float v) {
    v += __shfl_xor(v, 1);
    v += __shfl_xor(v, 2);
    v += __shfl_xor(v, 4);
    v += __shfl_xor(v, 8);
    v += __shfl_xor(v, 16);
    v += __shfl_xor(v, 32);
    return v;
}

// K1: h = zc_rms(x,g_norm); q=l2norm(h Wq); k=l2norm(h Wk); v=h Wv+bv;
//     gamma via direct DFT (bins 0..31) + band energies + MLP.
// One wave handles 8 rows; lane j owns output column j.
__global__ __launch_bounds__(256) void k1_proj_gamma(
    const float* __restrict__ x, const float* __restrict__ g_norm,
    const float* __restrict__ Wq, const float* __restrict__ Wk,
    const float* __restrict__ Wv, const float* __restrict__ bv,
    const float* __restrict__ W1, const float* __restrict__ b1,
    const float* __restrict__ W2, const float* __restrict__ b2,
    float* __restrict__ q_o, float* __restrict__ k_o,
    float* v_o, float* __restrict__ g_o)
{
    __shared__ float2 Tbl[64];     // (cos, sin)(2*pi*t/64)
    __shared__ float sW1[128];
    __shared__ float sb1[16];
    __shared__ float sW2[16];
    __shared__ float sb2;
    __shared__ float hbuf[4][8][64];

    int tid = threadIdx.x;
    if (tid < 64) {
        float ang = (2.0f * 3.14159265358979323846f / 64.0f) * (float)tid;
        Tbl[tid] = make_float2(cosf(ang), sinf(ang));
    } else if (tid < 192) {
        sW1[tid - 64] = W1[tid - 64];
    } else if (tid < 208) {
        sb1[tid - 192] = b1[tid - 192];
    } else if (tid < 224) {
        sW2[tid - 208] = W2[tid - 208];
    } else if (tid == 224) {
        sb2 = b2[0];
    }
    __syncthreads();

    int wave = tid >> 6;
    int lane = tid & 63;
    int f = lane & 31;                        // DFT bin; lanes 32..63 compute imag part
    int row0 = (blockIdx.x * 4 + wave) * 8;

    float gn = g_norm[lane];
    float h[8];
    #pragma unroll
    for (int r = 0; r < 8; ++r) {
        float xv = x[(row0 + r) * 64 + lane];
        float m = wsum(xv) * 0.015625f;
        float x0 = xv - m;
        float ms = wsum(x0 * x0) * 0.015625f;
        h[r] = x0 * rsqrtf(ms + 1e-8f) * gn;
        hbuf[wave][r][lane] = h[r];           // same-wave write->read: DS pipe in-order
    }

    float qa[8] = {}, ka[8] = {}, va[8] = {}, fa[8] = {};
    #pragma unroll 8
    for (int d = 0; d < 64; ++d) {
        float wq = Wq[d * 64 + lane];
        float wk = Wk[d * 64 + lane];
        float wv = Wv[d * 64 + lane];
        float2 cs = Tbl[(d * f) & 63];
        float tt = (lane < 32) ? cs.x : cs.y;
        #pragma unroll
        for (int r = 0; r < 8; ++r) {
            float hd = hbuf[wave][r][d];      // broadcast read
            qa[r] = fmaf(hd, wq, qa[r]);
            ka[r] = fmaf(hd, wk, ka[r]);
            va[r] = fmaf(hd, wv, va[r]);
            fa[r] = fmaf(hd, tt, fa[r]);
        }
    }

    float bvl = bv[lane];
    int t16 = lane & 15;
    #pragma unroll
    for (int r = 0; r < 8; ++r) {
        int idx = (row0 + r) * 64 + lane;
        float qss = wsum(qa[r] * qa[r]);              // l2norm uses SUM, eps 1e-8
        q_o[idx] = qa[r] * rsqrtf(qss + 1e-8f);
        float kss = wsum(ka[r] * ka[r]);
        k_o[idx] = ka[r] * rsqrtf(kss + 1e-8f);
        v_o[idx] = va[r] + bvl;

        // |F|: lane j<32 holds re(bin j), lane j+32 holds +sum of sin terms (|im|)
        float im = __shfl_xor(fa[r], 32);
        float mag = sqrtf(fa[r] * fa[r] + im * im);   // identical on j and j^32
        float s4 = mag + __shfl_xor(mag, 1);
        s4 += __shfl_xor(s4, 2);
        float e = s4 * 0.25f;                         // band energy, band i=(j>>2)&7
        float tot = e + __shfl_xor(e, 4);
        tot += __shfl_xor(tot, 8);
        tot += __shfl_xor(tot, 16);
        float en = e / fmaxf(tot, 1e-8f);
        float eall[8];
        #pragma unroll
        for (int i = 0; i < 8; ++i) eall[i] = __shfl(en, i << 2);
        // hidden unit t16 (replicated x4 across lane groups)
        float hs = sb1[t16];
        #pragma unroll
        for (int i = 0; i < 8; ++i) hs = fmaf(eall[i], sW1[i * 16 + t16], hs);
        float sig = 1.0f / (1.0f + __expf(-hs));
        float act = hs * sig;                          // silu
        float p = act * sW2[t16];
        p += __shfl_xor(p, 1);
        p += __shfl_xor(p, 2);
        p += __shfl_xor(p, 4);
        p += __shfl_xor(p, 8);
        float raw = 1.0f / (1.0f + __expf(-(p + sb2)));
        if (lane == 0) g_o[row0 + r] = fmaf(0.49f, raw, 0.5f);
    }
}

// K2: sequential delta-rule scan. One wave per batch; lane d owns S row d.
// v lives in d_out and is overwritten in place by o (v[t+1] prefetched before o[t] store).
__global__ __launch_bounds__(64) void k2_scan(
    const float* __restrict__ qw, const float* __restrict__ kw,
    const float* vw, const float* __restrict__ gw, float* ow)
{
    __shared__ __align__(16) float lk[2][64];
    __shared__ __align__(16) float lq[2][64];
    int b = blockIdx.x;
    int lane = threadIdx.x;
    const float* qb = qw + b * N_ * 64;
    const float* kb = kw + b * N_ * 64;
    const float* vb = vw + b * N_ * 64;
    const float* gb = gw + b * N_;
    float* ob = ow + b * N_ * 64;

    float S[64];
    #pragma unroll
    for (int e = 0; e < 64; ++e) S[e] = 0.0f;

    float kv = kb[lane], qv = qb[lane], vv = vb[lane];
    float gg = gb[0];

    for (int t = 0; t < N_; ++t) {
        int bf = t & 1;
        lk[bf][lane] = kv;
        lq[bf][lane] = qv;
        float vcur = vv, gcur = gg;
        if (t + 1 < N_) {                       // software prefetch next step
            kv = kb[(t + 1) * 64 + lane];
            qv = qb[(t + 1) * 64 + lane];
            vv = vb[(t + 1) * 64 + lane];
            gg = gb[t + 1];
        }
        __syncthreads();
        const float4* k4 = (const float4*)lk[bf];
        const float4* q4 = (const float4*)lq[bf];
        float4 kr[16];
        float p0 = 0, p1 = 0, p2 = 0, p3 = 0;
        #pragma unroll
        for (int c = 0; c < 16; ++c) {
            float4 kc = k4[c];
            kr[c] = kc;
            p0 = fmaf(S[4 * c + 0], kc.x, p0);
            p1 = fmaf(S[4 * c + 1], kc.y, p1);
            p2 = fmaf(S[4 * c + 2], kc.z, p2);
            p3 = fmaf(S[4 * c + 3], kc.w, p3);
        }
        float pred = (p0 + p1) + (p2 + p3);
        float delta = fminf(fmaxf(vcur - pred, -5.0f), 5.0f);
        float o0 = 0, o1 = 0, o2 = 0, o3 = 0;
        #pragma unroll
        for (int c = 0; c < 16; ++c) {
            float4 qc = q4[c];
            float4 kc = kr[c];
            float s;
            s = fminf(fmaxf(fmaf(gcur, S[4 * c + 0], delta * kc.x), -10.0f), 10.0f);
            S[4 * c + 0] = s; o0 = fmaf(s, qc.x, o0);
            s = fminf(fmaxf(fmaf(gcur, S[4 * c + 1], delta * kc.y), -10.0f), 10.0f);
            S[4 * c + 1] = s; o1 = fmaf(s, qc.y, o1);
            s = fminf(fmaxf(fmaf(gcur, S[4 * c + 2], delta * kc.z), -10.0f), 10.0f);
            S[4 * c + 2] = s; o2 = fmaf(s, qc.z, o2);
            s = fminf(fmaxf(fmaf(gcur, S[4 * c + 3], delta * kc.w), -10.0f), 10.0f);
            S[4 * c + 3] = s; o3 = fmaf(s, qc.w, o3);
        }
        ob[t * 64 + lane] = (o0 + o1) + (o2 + o3);
    }
}

// K3: out = x + zc_rms(o, g_post) @ Wo + bo, in place over d_out (o).
__global__ __launch_bounds__(256) void k3_epilogue(
    const float* __restrict__ x, const float* __restrict__ Wo,
    const float* __restrict__ bo, const float* __restrict__ g_post,
    float* out)
{
    __shared__ float hbuf[4][8][64];
    int tid = threadIdx.x;
    int wave = tid >> 6, lane = tid & 63;
    int row0 = (blockIdx.x * 4 + wave) * 8;
    float gp = g_post[lane];
    #pragma unroll
    for (int r = 0; r < 8; ++r) {
        float ov = out[(row0 + r) * 64 + lane];
        float m = wsum(ov) * 0.015625f;
        float x0 = ov - m;
        float ms = wsum(x0 * x0) * 0.015625f;
        hbuf[wave][r][lane] = x0 * rsqrtf(ms + 1e-8f) * gp;
    }
    float acc[8] = {};
    #pragma unroll 8
    for (int d = 0; d < 64; ++d) {
        float wo = Wo[d * 64 + lane];
        #pragma unroll
        for (int r = 0; r < 8; ++r) acc[r] = fmaf(hbuf[wave][r][d], wo, acc[r]);
    }
    float bol = bo[lane];
    #pragma unroll
    for (int r = 0; r < 8; ++r) {
        int idx = (row0 + r) * 64 + lane;
        out[idx] = acc[r] + bol + x[idx];
    }
}

extern "C" void kernel_launch(void* const* d_in, const int* in_sizes, int n_in,
                              void* d_out, int out_size, void* d_ws, size_t ws_size,
                              hipStream_t stream)
{
    const float* x      = (const float*)d_in[0];
    const float* g_norm = (const float*)d_in[1];
    const float* Wq     = (const float*)d_in[2];
    const float* Wk     = (const float*)d_in[3];
    const float* Wv     = (const float*)d_in[4];
    const float* bv     = (const float*)d_in[5];
    const float* Wo     = (const float*)d_in[6];
    const float* bo     = (const float*)d_in[7];
    const float* g_post = (const float*)d_in[8];
    const float* W1     = (const float*)d_in[9];
    const float* b1     = (const float*)d_in[10];
    const float* W2     = (const float*)d_in[11];
    const float* b2     = (const float*)d_in[12];
    float* out = (float*)d_out;

    float* qw = (float*)d_ws;                  // ROWS*64 floats
    float* kw = qw + (size_t)ROWS * 64;        // ROWS*64 floats
    float* gw = kw + (size_t)ROWS * 64;        // ROWS floats
    float* vw = out;                           // v staged in d_out, replaced by o in K2

    k1_proj_gamma<<<ROWS / 32, 256, 0, stream>>>(x, g_norm, Wq, Wk, Wv, bv,
                                                 W1, b1, W2, b2, qw, kw, vw, gw);
    k2_scan<<<B_, 64, 0, stream>>>(qw, kw, vw, gw, out);
    k3_epilogue<<<ROWS / 32, 256, 0, stream>>>(x, Wo, bo, g_post, out);
}

// Round 2
// 271.955 us; speedup vs baseline: 1.1497x; 1.1497x over previous
//
#include <hip/hip_runtime.h>
#include <math.h>

#define B_ 512
#define N_ 120
#define D_ 64
#define ROWS (B_ * N_)  // 61440

// K1: h = zc_rms(x,g_norm); q=l2norm(h Wq); k=l2norm(h Wk); v=h Wv+bv;
//     gamma via direct DFT (bins 0..31) + band energies + MLP.
// One wave handles 8 rows; lane j owns output column j.
__global__ __launch_bounds__(256) void k1_proj_gamma(
    const float* __restrict__ x, const float* __restrict__ g_norm,
    const float* __restrict__ Wq, const float* __restrict__ Wk,
    const float* __restrict__ Wv, const float* __restrict__ bv,
    const float* __restrict__ W1, const float* __restrict__ b1,
    const float* __restrict__ W2, const float* __restrict__ b2,
    float* __restrict__ q_o, float* __restrict__ k_o,
    float* v_o, float* __restrict__ g_o)
{
    __shared__ float2 Tbl[64];     // (cos, sin)(2*pi*t/64)
    __shared__ float sW1[128];
    __shared__ float sb1[16];
    __shared__ float sW2[16];
    __shared__ float sb2;
    __shared__ __align__(16) float hbuf[4][8][64];

    int tid = threadIdx.x;
    if (tid < 64) {
        float ang = (2.0f * 3.14159265358979323846f / 64.0f) * (float)tid;
        Tbl[tid] = make_float2(cosf(ang), sinf(ang));
    } else if (tid < 192) {
        sW1[tid - 64] = W1[tid - 64];
    } else if (tid < 208) {
        sb1[tid - 192] = b1[tid - 192];
    } else if (tid < 224) {
        sW2[tid - 208] = W2[tid - 208];
    } else if (tid == 224) {
        sb2 = b2[0];
    }
    __syncthreads();

    int wave = tid >> 6;
    int lane = tid & 63;
    int f = lane & 31;                        // DFT bin; lanes 32..63 compute imag part
    int row0 = (blockIdx.x * 4 + wave) * 8;

    float gn = g_norm[lane];
    // zc_rms via one paired pass: var = E[x^2] - mean^2 (identical to mean((x-m)^2))
    #pragma unroll
    for (int r = 0; r < 8; ++r) {
        float xv = x[(row0 + r) * 64 + lane];
        float sx = xv, sxx = xv * xv;
        #pragma unroll
        for (int m = 1; m < 64; m <<= 1) {
            sx  += __shfl_xor(sx, m);
            sxx += __shfl_xor(sxx, m);
        }
        float mean = sx * 0.015625f;
        float var  = sxx * 0.015625f - mean * mean;
        hbuf[wave][r][lane] = (xv - mean) * rsqrtf(var + 1e-8f) * gn;
    }

    float qa[8] = {}, ka[8] = {}, va[8] = {}, fa[8] = {};
    #pragma unroll 4
    for (int d4 = 0; d4 < 16; ++d4) {
        int d0 = d4 * 4;
        float wq0 = Wq[(d0 + 0) * 64 + lane], wq1 = Wq[(d0 + 1) * 64 + lane];
        float wq2 = Wq[(d0 + 2) * 64 + lane], wq3 = Wq[(d0 + 3) * 64 + lane];
        float wk0 = Wk[(d0 + 0) * 64 + lane], wk1 = Wk[(d0 + 1) * 64 + lane];
        float wk2 = Wk[(d0 + 2) * 64 + lane], wk3 = Wk[(d0 + 3) * 64 + lane];
        float wv0 = Wv[(d0 + 0) * 64 + lane], wv1 = Wv[(d0 + 1) * 64 + lane];
        float wv2 = Wv[(d0 + 2) * 64 + lane], wv3 = Wv[(d0 + 3) * 64 + lane];
        float2 c0 = Tbl[((d0 + 0) * f) & 63];
        float2 c1 = Tbl[((d0 + 1) * f) & 63];
        float2 c2 = Tbl[((d0 + 2) * f) & 63];
        float2 c3 = Tbl[((d0 + 3) * f) & 63];
        float tt0 = (lane < 32) ? c0.x : c0.y;
        float tt1 = (lane < 32) ? c1.x : c1.y;
        float tt2 = (lane < 32) ? c2.x : c2.y;
        float tt3 = (lane < 32) ? c3.x : c3.y;
        #pragma unroll
        for (int r = 0; r < 8; ++r) {
            float4 hd = *(const float4*)&hbuf[wave][r][d0];   // broadcast b128
            qa[r] = fmaf(hd.w, wq3, fmaf(hd.z, wq2, fmaf(hd.y, wq1, fmaf(hd.x, wq0, qa[r]))));
            ka[r] = fmaf(hd.w, wk3, fmaf(hd.z, wk2, fmaf(hd.y, wk1, fmaf(hd.x, wk0, ka[r]))));
            va[r] = fmaf(hd.w, wv3, fmaf(hd.z, wv2, fmaf(hd.y, wv1, fmaf(hd.x, wv0, va[r]))));
            fa[r] = fmaf(hd.w, tt3, fmaf(hd.z, tt2, fmaf(hd.y, tt1, fmaf(hd.x, tt0, fa[r]))));
        }
    }

    float bvl = bv[lane];
    int t16 = lane & 15;
    #pragma unroll
    for (int r = 0; r < 8; ++r) {
        int idx = (row0 + r) * 64 + lane;
        // paired l2norm reductions for q and k
        float qs = qa[r] * qa[r], ks = ka[r] * ka[r];
        #pragma unroll
        for (int m = 1; m < 64; m <<= 1) {
            qs += __shfl_xor(qs, m);
            ks += __shfl_xor(ks, m);
        }
        q_o[idx] = qa[r] * rsqrtf(qs + 1e-8f);
        k_o[idx] = ka[r] * rsqrtf(ks + 1e-8f);
        v_o[idx] = va[r] + bvl;

        // |F|: lane j<32 holds re(bin j), lane j+32 holds sum of sin terms (im)
        float im = __shfl_xor(fa[r], 32);
        float mag = sqrtf(fa[r] * fa[r] + im * im);   // identical on j and j^32
        float s4 = mag + __shfl_xor(mag, 1);
        s4 += __shfl_xor(s4, 2);
        float e = s4 * 0.25f;                         // band energy, band i=(j>>2)&7
        float tot = e + __shfl_xor(e, 4);
        tot += __shfl_xor(tot, 8);
        tot += __shfl_xor(tot, 16);
        float en = e / fmaxf(tot, 1e-8f);
        float eall[8];
        #pragma unroll
        for (int i = 0; i < 8; ++i) eall[i] = __shfl(en, i << 2);
        float hs = sb1[t16];
        #pragma unroll
        for (int i = 0; i < 8; ++i) hs = fmaf(eall[i], sW1[i * 16 + t16], hs);
        float sig = 1.0f / (1.0f + __expf(-hs));
        float act = hs * sig;                          // silu
        float p = act * sW2[t16];
        p += __shfl_xor(p, 1);
        p += __shfl_xor(p, 2);
        p += __shfl_xor(p, 4);
        p += __shfl_xor(p, 8);
        float raw = 1.0f / (1.0f + __expf(-(p + sb2)));
        if (lane == 0) g_o[row0 + r] = fmaf(0.49f, raw, 0.5f);
    }
}

// K2: sequential delta-rule scan, 4-way column-split.
// Block = 4 waves = one batch. Wave w owns rows [16w,16w+16).
// Lane l: dlo=l&15, h=l>>4; owns S[16w+dlo][16h..16h+16) in 16 VGPRs.
// pred/o reductions are in-wave shfl_xor(16/32). No LDS, no barriers.
// v lives in d_out and is overwritten in place by o (v[t+1] prefetched first).
__global__ __launch_bounds__(256) void k2_scan(
    const float* __restrict__ qw, const float* __restrict__ kw,
    const float* vw, const float* __restrict__ gw, float* ow)
{
    int b = blockIdx.x;
    int tid = threadIdx.x;
    int w = tid >> 6;
    int l = tid & 63;
    int dlo = l & 15;
    int h = l >> 4;
    int d = w * 16 + dlo;
    int eo = h * 16;                         // first owned column (float index)

    const float* qb = qw + (size_t)b * N_ * 64;
    const float* kb = kw + (size_t)b * N_ * 64;
    const float* vb = vw + (size_t)b * N_ * 64;
    const float* gb = gw + (size_t)b * N_;
    float* ob = ow + (size_t)b * N_ * 64;

    float4 S0 = make_float4(0.f, 0.f, 0.f, 0.f), S1 = S0, S2 = S0, S3 = S0;

    const float4* k4 = (const float4*)(kb + eo);
    const float4* q4 = (const float4*)(qb + eo);
    float4 kf0 = k4[0], kf1 = k4[1], kf2 = k4[2], kf3 = k4[3];
    float4 qf0 = q4[0], qf1 = q4[1], qf2 = q4[2], qf3 = q4[3];
    float vd = vb[d];
    float gt = gb[0];

    for (int t = 0; t < N_; ++t) {
        int tn = (t + 1 < N_) ? (t + 1) : t;           // uniform; last iter redundant
        const float4* k4n = (const float4*)(kb + tn * 64 + eo);
        const float4* q4n = (const float4*)(qb + tn * 64 + eo);
        float4 kn0 = k4n[0], kn1 = k4n[1], kn2 = k4n[2], kn3 = k4n[3];
        float4 qn0 = q4n[0], qn1 = q4n[1], qn2 = q4n[2], qn3 = q4n[3];
        float vn = vb[tn * 64 + d];
        float gn2 = gb[tn];

        // pred partial over owned 16 cols (4 independent chains)
        float pa = 0.f, pb = 0.f, pc = 0.f, pd = 0.f;
        pa = fmaf(S0.x, kf0.x, pa); pb = fmaf(S0.y, kf0.y, pb);
        pc = fmaf(S0.z, kf0.z, pc); pd = fmaf(S0.w, kf0.w, pd);
        pa = fmaf(S1.x, kf1.x, pa); pb = fmaf(S1.y, kf1.y, pb);
        pc = fmaf(S1.z, kf1.z, pc); pd = fmaf(S1.w, kf1.w, pd);
        pa = fmaf(S2.x, kf2.x, pa); pb = fmaf(S2.y, kf2.y, pb);
        pc = fmaf(S2.z, kf2.z, pc); pd = fmaf(S2.w, kf2.w, pd);
        pa = fmaf(S3.x, kf3.x, pa); pb = fmaf(S3.y, kf3.y, pb);
        pc = fmaf(S3.z, kf3.z, pc); pd = fmaf(S3.w, kf3.w, pd);
        float p = (pa + pb) + (pc + pd);
        p += __shfl_xor(p, 16);
        p += __shfl_xor(p, 32);

        float delta = fminf(fmaxf(vd - p, -5.0f), 5.0f);

        float o = 0.f, o2 = 0.f;
#define UPD(Sc, kc, qc)                                                        \
        Sc.x = fminf(fmaxf(fmaf(gt, Sc.x, delta * kc.x), -10.f), 10.f);        \
        o  = fmaf(Sc.x, qc.x, o);                                              \
        Sc.y = fminf(fmaxf(fmaf(gt, Sc.y, delta * kc.y), -10.f), 10.f);        \
        o2 = fmaf(Sc.y, qc.y, o2);                                             \
        Sc.z = fminf(fmaxf(fmaf(gt, Sc.z, delta * kc.z), -10.f), 10.f);        \
        o  = fmaf(Sc.z, qc.z, o);                                              \
        Sc.w = fminf(fmaxf(fmaf(gt, Sc.w, delta * kc.w), -10.f), 10.f);        \
        o2 = fmaf(Sc.w, qc.w, o2);
        UPD(S0, kf0, qf0)
        UPD(S1, kf1, qf1)
        UPD(S2, kf2, qf2)
        UPD(S3, kf3, qf3)
#undef UPD
        o += o2;
        o += __shfl_xor(o, 16);
        o += __shfl_xor(o, 32);
        if (h == 0) ob[t * 64 + d] = o;

        kf0 = kn0; kf1 = kn1; kf2 = kn2; kf3 = kn3;
        qf0 = qn0; qf1 = qn1; qf2 = qn2; qf3 = qn3;
        vd = vn; gt = gn2;
    }
}

// K3: out = x + zc_rms(o, g_post) @ Wo + bo, in place over d_out (o).
__global__ __launch_bounds__(256) void k3_epilogue(
    const float* __restrict__ x, const float* __restrict__ Wo,
    const float* __restrict__ bo, const float* __restrict__ g_post,
    float* out)
{
    __shared__ __align__(16) float hbuf[4][8][64];
    int tid = threadIdx.x;
    int wave = tid >> 6, lane = tid & 63;
    int row0 = (blockIdx.x * 4 + wave) * 8;
    float gp = g_post[lane];
    #pragma unroll
    for (int r = 0; r < 8; ++r) {
        float ov = out[(row0 + r) * 64 + lane];
        float sx = ov, sxx = ov * ov;
        #pragma unroll
        for (int m = 1; m < 64; m <<= 1) {
            sx  += __shfl_xor(sx, m);
            sxx += __shfl_xor(sxx, m);
        }
        float mean = sx * 0.015625f;
        float var  = sxx * 0.015625f - mean * mean;
        hbuf[wave][r][lane] = (ov - mean) * rsqrtf(var + 1e-8f) * gp;
    }
    float acc[8] = {};
    #pragma unroll 4
    for (int d4 = 0; d4 < 16; ++d4) {
        int d0 = d4 * 4;
        float wo0 = Wo[(d0 + 0) * 64 + lane], wo1 = Wo[(d0 + 1) * 64 + lane];
        float wo2 = Wo[(d0 + 2) * 64 + lane], wo3 = Wo[(d0 + 3) * 64 + lane];
        #pragma unroll
        for (int r = 0; r < 8; ++r) {
            float4 hd = *(const float4*)&hbuf[wave][r][d0];
            acc[r] = fmaf(hd.w, wo3, fmaf(hd.z, wo2, fmaf(hd.y, wo1, fmaf(hd.x, wo0, acc[r]))));
        }
    }
    float bol = bo[lane];
    #pragma unroll
    for (int r = 0; r < 8; ++r) {
        int idx = (row0 + r) * 64 + lane;
        out[idx] = acc[r] + bol + x[idx];
    }
}

extern "C" void kernel_launch(void* const* d_in, const int* in_sizes, int n_in,
                              void* d_out, int out_size, void* d_ws, size_t ws_size,
                              hipStream_t stream)
{
    const float* x      = (const float*)d_in[0];
    const float* g_norm = (const float*)d_in[1];
    const float* Wq     = (const float*)d_in[2];
    const float* Wk     = (const float*)d_in[3];
    const float* Wv     = (const float*)d_in[4];
    const float* bv     = (const float*)d_in[5];
    const float* Wo     = (const float*)d_in[6];
    const float* bo     = (const float*)d_in[7];
    const float* g_post = (const float*)d_in[8];
    const float* W1     = (const float*)d_in[9];
    const float* b1     = (const float*)d_in[10];
    const float* W2     = (const float*)d_in[11];
    const float* b2     = (const float*)d_in[12];
    float* out = (float*)d_out;

    float* qw = (float*)d_ws;                  // ROWS*64 floats
    float* kw = qw + (size_t)ROWS * 64;        // ROWS*64 floats
    float* gw = kw + (size_t)ROWS * 64;        // ROWS floats
    float* vw = out;                           // v staged in d_out, replaced by o in K2

    k1_proj_gamma<<<ROWS / 32, 256, 0, stream>>>(x, g_norm, Wq, Wk, Wv, bv,
                                                 W1, b1, W2, b2, qw, kw, vw, gw);
    k2_scan<<<B_, 256, 0, stream>>>(qw, kw, vw, gw, out);
    k3_epilogue<<<ROWS / 32, 256, 0, stream>>>(x, Wo, bo, g_post, out);
}

// Round 3
// 224.299 us; speedup vs baseline: 1.3939x; 1.2125x over previous
//
#include <hip/hip_runtime.h>
#include <math.h>

#define B_ 512
#define N_ 120
#define D_ 64
#define ROWS (B_ * N_)

// Fully fused KinematicDeltaNet: one block per batch, 8 waves.
// Phase 1: zc_rms + Q/K/V proj + DFT-gamma (8 waves x 15 rows, chunks of 5)
//          q,k -> d_ws (global, L2-hot); v -> d_out; gamma -> LDS.
// Phase 2: delta-rule scan; wave w owns S rows [8w,8w+8), lane l: row=w*8+(l&7),
//          cols [8*(l>>3), +8). No LDS/barriers inside loop; o_t -> LDS.
//          No global stores in the loop => no aliasing-induced vmcnt drains.
// Phase 3: out = x + zc_rms(o,g_post) @ Wo + bo, o read from LDS, in place over d_out.
__global__ __launch_bounds__(512, 4) void fused_kdn(
    const float* __restrict__ x, const float* __restrict__ g_norm,
    const float* __restrict__ Wq, const float* __restrict__ Wk,
    const float* __restrict__ Wv, const float* __restrict__ bv,
    const float* __restrict__ Wo, const float* __restrict__ bo,
    const float* __restrict__ g_post,
    const float* __restrict__ W1, const float* __restrict__ b1,
    const float* __restrict__ W2, const float* __restrict__ b2,
    float* __restrict__ qw, float* __restrict__ kw,
    float* out)
{
    __shared__ float2 Tbl[64];                    // (cos,sin)(2*pi*t/64)
    __shared__ float sW1[128];
    __shared__ float sb1[16];
    __shared__ float sW2[16];
    __shared__ float sb2;
    __shared__ float g_s[N_];
    __shared__ __align__(16) float hbuf[8][5][64];
    __shared__ __align__(16) float o_s[N_ * 64];  // 30.7 KB

    int tid = threadIdx.x;
    int wave = tid >> 6, lane = tid & 63;

    if (tid < 64) {
        float ang = (2.0f * 3.14159265358979323846f / 64.0f) * (float)tid;
        Tbl[tid] = make_float2(cosf(ang), sinf(ang));
    } else if (tid < 192) {
        sW1[tid - 64] = W1[tid - 64];
    } else if (tid < 208) {
        sb1[tid - 192] = b1[tid - 192];
    } else if (tid < 224) {
        sW2[tid - 208] = W2[tid - 208];
    } else if (tid == 224) {
        sb2 = b2[0];
    }
    __syncthreads();

    int b = blockIdx.x;
    const float* xb = x + (size_t)b * N_ * 64;
    float* qb = qw + (size_t)b * N_ * 64;
    float* kb = kw + (size_t)b * N_ * 64;
    float* vb = out + (size_t)b * N_ * 64;   // v staged in d_out; overwritten in phase 3

    float gn = g_norm[lane];
    float bvl = bv[lane];
    int f = lane & 31;                       // DFT bin (lanes 32..63: imag part)
    int t16 = lane & 15;

    // ---------------- Phase 1 ----------------
    for (int c = 0; c < 3; ++c) {
        int row0 = wave * 15 + c * 5;
        #pragma unroll
        for (int r = 0; r < 5; ++r) {
            float xv = xb[(row0 + r) * 64 + lane];
            float sx = xv, sxx = xv * xv;
            #pragma unroll
            for (int m = 1; m < 64; m <<= 1) {
                sx  += __shfl_xor(sx, m);
                sxx += __shfl_xor(sxx, m);
            }
            float mean = sx * 0.015625f;
            float var  = sxx * 0.015625f - mean * mean;
            hbuf[wave][r][lane] = (xv - mean) * rsqrtf(var + 1e-8f) * gn;
        }

        float qa[5] = {}, ka[5] = {}, va[5] = {}, fa[5] = {};
        #pragma unroll 4
        for (int d4 = 0; d4 < 16; ++d4) {
            int d0 = d4 * 4;
            float wq0 = Wq[(d0 + 0) * 64 + lane], wq1 = Wq[(d0 + 1) * 64 + lane];
            float wq2 = Wq[(d0 + 2) * 64 + lane], wq3 = Wq[(d0 + 3) * 64 + lane];
            float wk0 = Wk[(d0 + 0) * 64 + lane], wk1 = Wk[(d0 + 1) * 64 + lane];
            float wk2 = Wk[(d0 + 2) * 64 + lane], wk3 = Wk[(d0 + 3) * 64 + lane];
            float wv0 = Wv[(d0 + 0) * 64 + lane], wv1 = Wv[(d0 + 1) * 64 + lane];
            float wv2 = Wv[(d0 + 2) * 64 + lane], wv3 = Wv[(d0 + 3) * 64 + lane];
            float2 c0 = Tbl[((d0 + 0) * f) & 63];
            float2 c1 = Tbl[((d0 + 1) * f) & 63];
            float2 c2 = Tbl[((d0 + 2) * f) & 63];
            float2 c3 = Tbl[((d0 + 3) * f) & 63];
            float tt0 = (lane < 32) ? c0.x : c0.y;
            float tt1 = (lane < 32) ? c1.x : c1.y;
            float tt2 = (lane < 32) ? c2.x : c2.y;
            float tt3 = (lane < 32) ? c3.x : c3.y;
            #pragma unroll
            for (int r = 0; r < 5; ++r) {
                float4 hd = *(const float4*)&hbuf[wave][r][d0];
                qa[r] = fmaf(hd.w, wq3, fmaf(hd.z, wq2, fmaf(hd.y, wq1, fmaf(hd.x, wq0, qa[r]))));
                ka[r] = fmaf(hd.w, wk3, fmaf(hd.z, wk2, fmaf(hd.y, wk1, fmaf(hd.x, wk0, ka[r]))));
                va[r] = fmaf(hd.w, wv3, fmaf(hd.z, wv2, fmaf(hd.y, wv1, fmaf(hd.x, wv0, va[r]))));
                fa[r] = fmaf(hd.w, tt3, fmaf(hd.z, tt2, fmaf(hd.y, tt1, fmaf(hd.x, tt0, fa[r]))));
            }
        }

        #pragma unroll
        for (int r = 0; r < 5; ++r) {
            int row = row0 + r;
            int idx = row * 64 + lane;
            float qs = qa[r] * qa[r], ks = ka[r] * ka[r];
            #pragma unroll
            for (int m = 1; m < 64; m <<= 1) {
                qs += __shfl_xor(qs, m);
                ks += __shfl_xor(ks, m);
            }
            qb[idx] = qa[r] * rsqrtf(qs + 1e-8f);
            kb[idx] = ka[r] * rsqrtf(ks + 1e-8f);
            vb[idx] = va[r] + bvl;

            float im = __shfl_xor(fa[r], 32);
            float mag = sqrtf(fa[r] * fa[r] + im * im);
            float s4 = mag + __shfl_xor(mag, 1);
            s4 += __shfl_xor(s4, 2);
            float e = s4 * 0.25f;                      // band energy, band=(f>>2)
            float tot = e + __shfl_xor(e, 4);
            tot += __shfl_xor(tot, 8);
            tot += __shfl_xor(tot, 16);
            float en = e / fmaxf(tot, 1e-8f);
            float eall[8];
            #pragma unroll
            for (int i = 0; i < 8; ++i) eall[i] = __shfl(en, i << 2);
            float hs = sb1[t16];
            #pragma unroll
            for (int i = 0; i < 8; ++i) hs = fmaf(eall[i], sW1[i * 16 + t16], hs);
            float sig = 1.0f / (1.0f + __expf(-hs));
            float act = hs * sig;                      // silu
            float p = act * sW2[t16];
            p += __shfl_xor(p, 1);
            p += __shfl_xor(p, 2);
            p += __shfl_xor(p, 4);
            p += __shfl_xor(p, 8);
            float raw = 1.0f / (1.0f + __expf(-(p + sb2)));
            if (lane == 0) g_s[row] = fmaf(0.49f, raw, 0.5f);
        }
    }
    __syncthreads();

    // ---------------- Phase 2: scan ----------------
    {
        int dlo = lane & 7, grp = lane >> 3;
        int d = wave * 8 + dlo;
        int co = grp * 8;

        float4 S0 = make_float4(0.f, 0.f, 0.f, 0.f), S1 = S0;

        const float4* k40 = (const float4*)(kb + co);
        const float4* q40 = (const float4*)(qb + co);
        float4 kf0 = k40[0], kf1 = k40[1];
        float4 qf0 = q40[0], qf1 = q40[1];
        float vd = vb[d];
        float gt = g_s[0];

        for (int t = 0; t < N_; ++t) {
            int tn = (t + 1 < N_) ? (t + 1) : t;
            const float4* k4n = (const float4*)(kb + tn * 64 + co);
            const float4* q4n = (const float4*)(qb + tn * 64 + co);
            float4 kn0 = k4n[0], kn1 = k4n[1];
            float4 qn0 = q4n[0], qn1 = q4n[1];
            float vn = vb[tn * 64 + d];
            float gtn = g_s[tn];

            float pa = fmaf(S0.x, kf0.x, fmaf(S0.z, kf0.z, fmaf(S1.x, kf1.x, S1.z * kf1.z)));
            float pb = fmaf(S0.y, kf0.y, fmaf(S0.w, kf0.w, fmaf(S1.y, kf1.y, S1.w * kf1.w)));
            float p = pa + pb;
            p += __shfl_xor(p, 8);
            p += __shfl_xor(p, 16);
            p += __shfl_xor(p, 32);

            float delta = fminf(fmaxf(vd - p, -5.0f), 5.0f);

            float o = 0.f, o2 = 0.f;
#define UPD(Sc, kc, qc)                                                        \
            Sc.x = fminf(fmaxf(fmaf(gt, Sc.x, delta * kc.x), -10.f), 10.f);    \
            o  = fmaf(Sc.x, qc.x, o);                                          \
            Sc.y = fminf(fmaxf(fmaf(gt, Sc.y, delta * kc.y), -10.f), 10.f);    \
            o2 = fmaf(Sc.y, qc.y, o2);                                         \
            Sc.z = fminf(fmaxf(fmaf(gt, Sc.z, delta * kc.z), -10.f), 10.f);    \
            o  = fmaf(Sc.z, qc.z, o);                                          \
            Sc.w = fminf(fmaxf(fmaf(gt, Sc.w, delta * kc.w), -10.f), 10.f);    \
            o2 = fmaf(Sc.w, qc.w, o2);
            UPD(S0, kf0, qf0)
            UPD(S1, kf1, qf1)
#undef UPD
            o += o2;
            o += __shfl_xor(o, 8);
            o += __shfl_xor(o, 16);
            o += __shfl_xor(o, 32);
            if (grp == 0) o_s[t * 64 + d] = o;

            kf0 = kn0; kf1 = kn1; qf0 = qn0; qf1 = qn1;
            vd = vn; gt = gtn;
        }
    }
    __syncthreads();

    // ---------------- Phase 3: epilogue ----------------
    float gp = g_post[lane];
    float bol = bo[lane];
    for (int c = 0; c < 3; ++c) {
        int row0 = wave * 15 + c * 5;
        #pragma unroll
        for (int r = 0; r < 5; ++r) {
            float ov = o_s[(row0 + r) * 64 + lane];
            float sx = ov, sxx = ov * ov;
            #pragma unroll
            for (int m = 1; m < 64; m <<= 1) {
                sx  += __shfl_xor(sx, m);
                sxx += __shfl_xor(sxx, m);
            }
            float mean = sx * 0.015625f;
            float var  = sxx * 0.015625f - mean * mean;
            hbuf[wave][r][lane] = (ov - mean) * rsqrtf(var + 1e-8f) * gp;
        }
        float acc[5] = {};
        #pragma unroll 4
        for (int d4 = 0; d4 < 16; ++d4) {
            int d0 = d4 * 4;
            float wo0 = Wo[(d0 + 0) * 64 + lane], wo1 = Wo[(d0 + 1) * 64 + lane];
            float wo2 = Wo[(d0 + 2) * 64 + lane], wo3 = Wo[(d0 + 3) * 64 + lane];
            #pragma unroll
            for (int r = 0; r < 5; ++r) {
                float4 hd = *(const float4*)&hbuf[wave][r][d0];
                acc[r] = fmaf(hd.w, wo3, fmaf(hd.z, wo2, fmaf(hd.y, wo1, fmaf(hd.x, wo0, acc[r]))));
            }
        }
        #pragma unroll
        for (int r = 0; r < 5; ++r) {
            int idx = (row0 + r) * 64 + lane;
            vb[idx] = acc[r] + bol + xb[idx];   // final out, in place over v
        }
    }
}

extern "C" void kernel_launch(void* const* d_in, const int* in_sizes, int n_in,
                              void* d_out, int out_size, void* d_ws, size_t ws_size,
                              hipStream_t stream)
{
    const float* x      = (const float*)d_in[0];
    const float* g_norm = (const float*)d_in[1];
    const float* Wq     = (const float*)d_in[2];
    const float* Wk     = (const float*)d_in[3];
    const float* Wv     = (const float*)d_in[4];
    const float* bv     = (const float*)d_in[5];
    const float* Wo     = (const float*)d_in[6];
    const float* bo     = (const float*)d_in[7];
    const float* g_post = (const float*)d_in[8];
    const float* W1     = (const float*)d_in[9];
    const float* b1     = (const float*)d_in[10];
    const float* W2     = (const float*)d_in[11];
    const float* b2     = (const float*)d_in[12];
    float* out = (float*)d_out;

    float* qw = (float*)d_ws;                  // ROWS*64 floats
    float* kw = qw + (size_t)ROWS * 64;        // ROWS*64 floats  (total 31.5 MB, proven fit)

    fused_kdn<<<B_, 512, 0, stream>>>(x, g_norm, Wq, Wk, Wv, bv, Wo, bo, g_post,
                                      W1, b1, W2, b2, qw, kw, out);
}

// Round 4
// 183.092 us; speedup vs baseline: 1.7076x; 1.2251x over previous
//
#include <hip/hip_runtime.h>
#include <math.h>

#define B_ 512
#define N_ 120

typedef __attribute__((ext_vector_type(8))) _Float16 f16x8;
typedef __attribute__((ext_vector_type(2))) _Float16 f16x2;
typedef __attribute__((ext_vector_type(4))) float f32x4;

// 4 N-tiles of D = A(16x64) * W(64x64) via 16x16x32 f16 MFMA (2 k-steps each).
// wmat is in B-frag order: vec-index = ntile*128 + kstep*64 + lane.
__device__ __forceinline__ void mm4(f16x8 a0, f16x8 a1, const _Float16* wmat,
                                    int lane, f32x4* acc) {
    const f16x8* wv = (const f16x8*)wmat;
    #pragma unroll
    for (int nt = 0; nt < 4; ++nt) {
        f32x4 z = {0.f, 0.f, 0.f, 0.f};
        z = __builtin_amdgcn_mfma_f32_16x16x32_f16(a0, wv[nt * 128 + lane], z, 0, 0, 0);
        z = __builtin_amdgcn_mfma_f32_16x16x32_f16(a1, wv[nt * 128 + 64 + lane], z, 0, 0, 0);
        acc[nt] = z;
    }
}

// Fully fused KinematicDeltaNet, one block (8 waves) per batch.
// A-frag layout (16x16x32): lane holds A[m=lane&15][k=(lane>>4)*8+j]; LDS order
// tile*1024 + kstep*512 + lane*8 + j  => frag load = ds_read_b128 at lane*16B.
// C/D: col=lane&15, row=(lane>>4)*4+reg  [guide §3, m89/m91 verified].
__global__ __launch_bounds__(512, 4) void fused_kdn(
    const float* __restrict__ x, const float* __restrict__ g_norm,
    const float* __restrict__ Wq, const float* __restrict__ Wk,
    const float* __restrict__ Wv, const float* __restrict__ bv,
    const float* __restrict__ Wo, const float* __restrict__ bo,
    const float* __restrict__ g_post,
    const float* __restrict__ W1, const float* __restrict__ b1,
    const float* __restrict__ W2, const float* __restrict__ b2,
    float* __restrict__ qw, float* __restrict__ kw,
    float* out)
{
    __shared__ __align__(16) _Float16 Wf[4 * 4096];  // B-frag slots: Wq,Wk,Wv,T (32 KB)
    __shared__ __align__(16) _Float16 hf[8192];      // A-frag h / zc_rms(o)  (16 KB)
    __shared__ float g_s[N_];
    __shared__ float bv_s[64], bo_s[64];
    __shared__ float sW1[128], sb1[16], sW2[16], sb2_s[1];
    _Float16* o_s = Wf + 4096;                       // scan output aliases dead Wk/Wv slots

    int tid = threadIdx.x, wave = tid >> 6, lane = tid & 63;
    int b = blockIdx.x;

    // ---------------- setup: small arrays, zero hf, stage weights ----------------
    if (tid < 128) sW1[tid] = W1[tid];
    else if (tid < 144) sb1[tid - 128] = b1[tid - 128];
    else if (tid < 160) sW2[tid - 144] = W2[tid - 144];
    else if (tid == 160) sb2_s[0] = b2[0];
    else if (tid >= 192 && tid < 256) bv_s[tid - 192] = bv[tid - 192];
    else if (tid >= 256 && tid < 320) bo_s[tid - 256] = bo[tid - 256];

    {   // zero hf (A-pad rows 120..127 must be 0; rest overwritten in stage 1)
        f16x8 z = {0, 0, 0, 0, 0, 0, 0, 0};
        *(f16x8*)&hf[tid * 16] = z;
        *(f16x8*)&hf[tid * 16 + 8] = z;
    }
    int sn = tid & 63, sk0 = (tid >> 6) * 8;
    int widx = (sn >> 4) * 1024 + (sk0 >> 5) * 512 + ((((sk0 >> 3) & 3) << 4) + (sn & 15)) * 8;
    {
        const float* Ws[3] = { Wq, Wk, Wv };
        #pragma unroll
        for (int m = 0; m < 3; ++m) {
            f16x8 pv;
            #pragma unroll
            for (int j = 0; j < 8; ++j) pv[j] = (_Float16)Ws[m][(sk0 + j) * 64 + sn];
            *(f16x8*)&Wf[m * 4096 + widx] = pv;
        }
        // DFT table slot 3: T[k][n] = n<32 ? cos(2pi k n/64) : sin(2pi k (n-32)/64)
        f16x8 pv;
        int nn = sn & 31;
        #pragma unroll
        for (int j = 0; j < 8; ++j) {
            int kk = ((sk0 + j) * nn) & 63;
            float a = (float)kk * (6.283185307179586f / 64.0f);
            float s, c; __sincosf(a, &s, &c);
            pv[j] = (_Float16)((sn < 32) ? c : s);
        }
        *(f16x8*)&Wf[3 * 4096 + widx] = pv;
    }
    __syncthreads();

    const float* xb = x + (size_t)b * N_ * 64;
    float* qb = qw + (size_t)b * N_ * 64;
    float* kb = kw + (size_t)b * N_ * 64;
    float* vb = out + (size_t)b * N_ * 64;   // v staged in d_out, overwritten in stage 4

    // ---------------- stage 1: zc_rms -> hf (A-frag order, fp16) ----------------
    {
        float gn = g_norm[lane];
        int hbase = (lane >> 5) * 512 + ((lane >> 3) & 3) * 128 + (lane & 7);
        #pragma unroll 5
        for (int c = 0; c < 15; ++c) {
            int row = wave * 15 + c;
            float xv = xb[row * 64 + lane];
            float sx = xv, sxx = xv * xv;
            #pragma unroll
            for (int m = 1; m < 64; m <<= 1) { sx += __shfl_xor(sx, m); sxx += __shfl_xor(sxx, m); }
            float mean = sx * 0.015625f;
            float var  = sxx * 0.015625f - mean * mean;
            float h = (xv - mean) * rsqrtf(var + 1e-8f) * gn;
            float hp = __shfl_xor(h, 1);
            if (!(lane & 1)) {
                f16x2 pk2 = { (_Float16)h, (_Float16)hp };
                *(f16x2*)&hf[(row >> 4) * 1024 + (row & 15) * 8 + hbase] = pk2;
            }
        }
    }
    __syncthreads();

    // ---------------- stage 2: MFMA projections + l2norm + gamma ----------------
    {
        const f16x8* hfv = (const f16x8*)hf;
        f16x8 a0 = hfv[wave * 128 + lane];
        f16x8 a1 = hfv[wave * 128 + 64 + lane];
        int grp = lane >> 4, li = lane & 15;
        int rbase = wave * 16 + grp * 4;
        f32x4 acc[4];

        // q
        mm4(a0, a1, Wf, lane, acc);
        {
            f32x4 ss = acc[0] * acc[0] + acc[1] * acc[1] + acc[2] * acc[2] + acc[3] * acc[3];
            #pragma unroll
            for (int reg = 0; reg < 4; ++reg) {
                float s = ss[reg];
                s += __shfl_xor(s, 1); s += __shfl_xor(s, 2);
                s += __shfl_xor(s, 4); s += __shfl_xor(s, 8);
                float r = rsqrtf(s + 1e-8f);
                int row = rbase + reg;
                if (row < N_) {
                    #pragma unroll
                    for (int nt = 0; nt < 4; ++nt)
                        qb[row * 64 + nt * 16 + li] = acc[nt][reg] * r;
                }
            }
        }
        // k
        mm4(a0, a1, Wf + 4096, lane, acc);
        {
            f32x4 ss = acc[0] * acc[0] + acc[1] * acc[1] + acc[2] * acc[2] + acc[3] * acc[3];
            #pragma unroll
            for (int reg = 0; reg < 4; ++reg) {
                float s = ss[reg];
                s += __shfl_xor(s, 1); s += __shfl_xor(s, 2);
                s += __shfl_xor(s, 4); s += __shfl_xor(s, 8);
                float r = rsqrtf(s + 1e-8f);
                int row = rbase + reg;
                if (row < N_) {
                    #pragma unroll
                    for (int nt = 0; nt < 4; ++nt)
                        kb[row * 64 + nt * 16 + li] = acc[nt][reg] * r;
                }
            }
        }
        // v
        mm4(a0, a1, Wf + 2 * 4096, lane, acc);
        {
            float b0v = bv_s[li], b1v = bv_s[16 + li], b2v = bv_s[32 + li], b3v = bv_s[48 + li];
            #pragma unroll
            for (int reg = 0; reg < 4; ++reg) {
                int row = rbase + reg;
                if (row < N_) {
                    vb[row * 64 +      li] = acc[0][reg] + b0v;
                    vb[row * 64 + 16 + li] = acc[1][reg] + b1v;
                    vb[row * 64 + 32 + li] = acc[2][reg] + b2v;
                    vb[row * 64 + 48 + li] = acc[3][reg] + b3v;
                }
            }
        }
        // gamma: |rfft| bins 0..31 (re: ntiles 0,1; im: ntiles 2,3), bands, MLP
        mm4(a0, a1, Wf + 3 * 4096, lane, acc);
        {
            int gb2 = lane & 48;
            #pragma unroll
            for (int reg = 0; reg < 4; ++reg) {
                float re1 = acc[0][reg], re2 = acc[1][reg];
                float im1 = acc[2][reg], im2 = acc[3][reg];
                float m1 = sqrtf(fmaf(re1, re1, im1 * im1));
                float m2 = sqrtf(fmaf(re2, re2, im2 * im2));
                m1 += __shfl_xor(m1, 1); m2 += __shfl_xor(m2, 1);
                m1 += __shfl_xor(m1, 2); m2 += __shfl_xor(m2, 2);
                float e1 = m1 * 0.25f, e2 = m2 * 0.25f;       // bands li>>2, 4+(li>>2)
                float tot = e1 + e2;
                tot += __shfl_xor(tot, 4); tot += __shfl_xor(tot, 8);
                float rinv = 1.0f / fmaxf(tot, 1e-8f);
                float en1 = e1 * rinv, en2 = e2 * rinv;
                float hs = sb1[li];
                #pragma unroll
                for (int i = 0; i < 4; ++i)
                    hs = fmaf(__shfl(en1, gb2 + (i << 2)), sW1[i * 16 + li], hs);
                #pragma unroll
                for (int i = 0; i < 4; ++i)
                    hs = fmaf(__shfl(en2, gb2 + (i << 2)), sW1[(i + 4) * 16 + li], hs);
                float act = hs / (1.0f + __expf(-hs));        // silu
                float p = act * sW2[li];
                p += __shfl_xor(p, 1); p += __shfl_xor(p, 2);
                p += __shfl_xor(p, 4); p += __shfl_xor(p, 8);
                float raw = 1.0f / (1.0f + __expf(-(p + sb2_s[0])));
                int row = rbase + reg;
                if (li == 0 && row < N_) g_s[row] = fmaf(0.49f, raw, 0.5f);
            }
        }
    }
    __syncthreads();

    // restage Wo into dead Wq slot (scan never touches Wf slot 0 or hf)
    {
        f16x8 pv;
        #pragma unroll
        for (int j = 0; j < 8; ++j) pv[j] = (_Float16)Wo[(sk0 + j) * 64 + sn];
        *(f16x8*)&Wf[widx] = pv;
    }

    // ---------------- stage 3: delta-rule scan (o -> o_s fp16, no global stores) ----
    {
        int dlo = lane & 7, g8 = lane >> 3;
        int d = wave * 8 + dlo;
        int co = g8 * 8;
        float4 S0 = make_float4(0.f, 0.f, 0.f, 0.f), S1 = S0;
        const float4* k40 = (const float4*)(kb + co);
        const float4* q40 = (const float4*)(qb + co);
        float4 kf0 = k40[0], kf1 = k40[1];
        float4 qf0 = q40[0], qf1 = q40[1];
        float vd = vb[d];
        float gt = g_s[0];
        for (int t = 0; t < N_; ++t) {
            int tn = (t + 1 < N_) ? (t + 1) : t;
            const float4* k4n = (const float4*)(kb + tn * 64 + co);
            const float4* q4n = (const float4*)(qb + tn * 64 + co);
            float4 kn0 = k4n[0], kn1 = k4n[1];
            float4 qn0 = q4n[0], qn1 = q4n[1];
            float vn = vb[tn * 64 + d];
            float gtn = g_s[tn];

            float pa = fmaf(S0.x, kf0.x, fmaf(S0.z, kf0.z, fmaf(S1.x, kf1.x, S1.z * kf1.z)));
            float pb = fmaf(S0.y, kf0.y, fmaf(S0.w, kf0.w, fmaf(S1.y, kf1.y, S1.w * kf1.w)));
            float p = pa + pb;
            p += __shfl_xor(p, 8); p += __shfl_xor(p, 16); p += __shfl_xor(p, 32);

            float delta = fminf(fmaxf(vd - p, -5.0f), 5.0f);

            float o = 0.f, o2 = 0.f;
#define UPD(Sc, kc, qc)                                                        \
            Sc.x = fminf(fmaxf(fmaf(gt, Sc.x, delta * kc.x), -10.f), 10.f);    \
            o  = fmaf(Sc.x, qc.x, o);                                          \
            Sc.y = fminf(fmaxf(fmaf(gt, Sc.y, delta * kc.y), -10.f), 10.f);    \
            o2 = fmaf(Sc.y, qc.y, o2);                                         \
            Sc.z = fminf(fmaxf(fmaf(gt, Sc.z, delta * kc.z), -10.f), 10.f);    \
            o  = fmaf(Sc.z, qc.z, o);                                          \
            Sc.w = fminf(fmaxf(fmaf(gt, Sc.w, delta * kc.w), -10.f), 10.f);    \
            o2 = fmaf(Sc.w, qc.w, o2);
            UPD(S0, kf0, qf0)
            UPD(S1, kf1, qf1)
#undef UPD
            o += o2;
            o += __shfl_xor(o, 8); o += __shfl_xor(o, 16); o += __shfl_xor(o, 32);
            if (g8 == 0) o_s[t * 64 + d] = (_Float16)o;

            kf0 = kn0; kf1 = kn1; qf0 = qn0; qf1 = qn1;
            vd = vn; gt = gtn;
        }
    }
    __syncthreads();

    // ---------------- stage 4a: zc_rms(o) -> hf (A-frag fp16) ----------------
    {
        float gp = g_post[lane];
        int hbase = (lane >> 5) * 512 + ((lane >> 3) & 3) * 128 + (lane & 7);
        #pragma unroll 5
        for (int c = 0; c < 15; ++c) {
            int row = wave * 15 + c;
            float ov = (float)o_s[row * 64 + lane];
            float sx = ov, sxx = ov * ov;
            #pragma unroll
            for (int m = 1; m < 64; m <<= 1) { sx += __shfl_xor(sx, m); sxx += __shfl_xor(sxx, m); }
            float mean = sx * 0.015625f;
            float var  = sxx * 0.015625f - mean * mean;
            float hn = (ov - mean) * rsqrtf(var + 1e-8f) * gp;
            float hp = __shfl_xor(hn, 1);
            if (!(lane & 1)) {
                f16x2 pk2 = { (_Float16)hn, (_Float16)hp };
                *(f16x2*)&hf[(row >> 4) * 1024 + (row & 15) * 8 + hbase] = pk2;
            }
        }
    }
    __syncthreads();

    // ---------------- stage 4b: out = x + zc_rms(o) @ Wo + bo ----------------
    {
        const f16x8* hfv = (const f16x8*)hf;
        f16x8 a0 = hfv[wave * 128 + lane];
        f16x8 a1 = hfv[wave * 128 + 64 + lane];
        int grp = lane >> 4, li = lane & 15;
        int rbase = wave * 16 + grp * 4;
        f32x4 acc[4];
        mm4(a0, a1, Wf, lane, acc);   // slot 0 = Wo now
        float b0o = bo_s[li], b1o = bo_s[16 + li], b2o = bo_s[32 + li], b3o = bo_s[48 + li];
        #pragma unroll
        for (int reg = 0; reg < 4; ++reg) {
            int row = rbase + reg;
            if (row < N_) {
                vb[row * 64 +      li] = acc[0][reg] + b0o + xb[row * 64 +      li];
                vb[row * 64 + 16 + li] = acc[1][reg] + b1o + xb[row * 64 + 16 + li];
                vb[row * 64 + 32 + li] = acc[2][reg] + b2o + xb[row * 64 + 32 + li];
                vb[row * 64 + 48 + li] = acc[3][reg] + b3o + xb[row * 64 + 48 + li];
            }
        }
    }
}

extern "C" void kernel_launch(void* const* d_in, const int* in_sizes, int n_in,
                              void* d_out, int out_size, void* d_ws, size_t ws_size,
                              hipStream_t stream)
{
    const float* x      = (const float*)d_in[0];
    const float* g_norm = (const float*)d_in[1];
    const float* Wq     = (const float*)d_in[2];
    const float* Wk     = (const float*)d_in[3];
    const float* Wv     = (const float*)d_in[4];
    const float* bv     = (const float*)d_in[5];
    const float* Wo     = (const float*)d_in[6];
    const float* bo     = (const float*)d_in[7];
    const float* g_post = (const float*)d_in[8];
    const float* W1     = (const float*)d_in[9];
    const float* b1     = (const float*)d_in[10];
    const float* W2     = (const float*)d_in[11];
    const float* b2     = (const float*)d_in[12];
    float* out = (float*)d_out;

    float* qw = (float*)d_ws;                  // B_*N_*64 floats
    float* kw = qw + (size_t)B_ * N_ * 64;     // B_*N_*64 floats

    fused_kdn<<<B_, 512, 0, stream>>>(x, g_norm, Wq, Wk, Wv, bv, Wo, bo, g_post,
                                      W1, b1, W2, b2, qw, kw, out);
}

// Round 5
// 179.529 us; speedup vs baseline: 1.7415x; 1.0198x over previous
//
#include <hip/hip_runtime.h>
#include <math.h>

#define B_ 512
#define N_ 120

typedef __attribute__((ext_vector_type(8))) _Float16 f16x8;
typedef __attribute__((ext_vector_type(2))) _Float16 f16x2;
typedef __attribute__((ext_vector_type(4))) float f32x4;

// LDS union buffer offsets (f16 units):
//  phase A (setup..stage2): Wq 0 | Wk 4096 | Wv 8192 | T 12288 | xf 16384..24576
//  phase B (scan):          q_s 0 | k_s 7680 | v_s 15360 | o_f 23040..31232
//  persistent:              Wo 31232..35328
#define OFF_WQ 0
#define OFF_WK 4096
#define OFF_WV 8192
#define OFF_T  12288
#define OFF_XF 16384
#define OFF_QS 0
#define OFF_KS 7680
#define OFF_VS 15360
#define OFF_OF 23040
#define OFF_WO 31232
#define LDS_F16 35328

// 4 N-tiles of D = A(16x64) * W(64x64) via 16x16x32 f16 MFMA (2 k-steps each).
// wmat in B-frag order: vec-index = ntile*128 + kstep*64 + lane.
__device__ __forceinline__ void mm4(f16x8 a0, f16x8 a1, const _Float16* wmat,
                                    int lane, f32x4* acc) {
    const f16x8* wv = (const f16x8*)wmat;
    #pragma unroll
    for (int nt = 0; nt < 4; ++nt) {
        f32x4 z = {0.f, 0.f, 0.f, 0.f};
        z = __builtin_amdgcn_mfma_f32_16x16x32_f16(a0, wv[nt * 128 + lane], z, 0, 0, 0);
        z = __builtin_amdgcn_mfma_f32_16x16x32_f16(a1, wv[nt * 128 + 64 + lane], z, 0, 0, 0);
        acc[nt] = z;
    }
}

// A-frag element index for A[row][d] (16x16x32, tiles of 16 rows):
// (row>>4)*1024 + (d>>5)*512 + ((d>>3)&3)*128 + (row&15)*8 + (d&7)
__global__ __launch_bounds__(512, 4) void fused_kdn(
    const float* __restrict__ x, const float* __restrict__ g_norm,
    const float* __restrict__ Wq, const float* __restrict__ Wk,
    const float* __restrict__ Wv, const float* __restrict__ bv,
    const float* __restrict__ Wo, const float* __restrict__ bo,
    const float* __restrict__ g_post,
    const float* __restrict__ W1, const float* __restrict__ b1,
    const float* __restrict__ W2, const float* __restrict__ b2,
    float* out)
{
    __shared__ __align__(16) _Float16 L[LDS_F16];
    __shared__ float g_s[N_];
    __shared__ float bv_s[64], bo_s[64];
    __shared__ float sW1[128], sb1[16], sW2[16], sb2_s[1];

    int tid = threadIdx.x, wave = tid >> 6, lane = tid & 63;
    int b = blockIdx.x;

    // ---------------- setup ----------------
    if (tid < 128) sW1[tid] = W1[tid];
    if (tid >= 128 && tid < 144) sb1[tid - 128] = b1[tid - 128];
    if (tid >= 144 && tid < 160) sW2[tid - 144] = W2[tid - 144];
    if (tid == 160) sb2_s[0] = b2[0];
    if (tid >= 192 && tid < 256) bv_s[tid - 192] = bv[tid - 192];
    if (tid >= 256 && tid < 320) bo_s[tid - 256] = bo[tid - 256];
    if (tid < 128) {   // zero A-frag tile 7 (pad rows 120..127) for xf and o_f
        f16x8 z = {0, 0, 0, 0, 0, 0, 0, 0};
        *(f16x8*)&L[OFF_XF + 7168 + tid * 8] = z;
        *(f16x8*)&L[OFF_OF + 7168 + tid * 8] = z;
    }
    int sn = tid & 63, sk0 = (tid >> 6) * 8;
    int widx = (sn >> 4) * 1024 + (sk0 >> 5) * 512 + ((((sk0 >> 3) & 3) << 4) + (sn & 15)) * 8;
    {
        const float* Ws[4] = { Wq, Wk, Wv, Wo };
        const int woff[4] = { OFF_WQ, OFF_WK, OFF_WV, OFF_WO };
        #pragma unroll
        for (int m = 0; m < 4; ++m) {
            f16x8 pv;
            #pragma unroll
            for (int j = 0; j < 8; ++j) pv[j] = (_Float16)Ws[m][(sk0 + j) * 64 + sn];
            *(f16x8*)&L[woff[m] + widx] = pv;
        }
        // DFT table: T[k][n] = n<32 ? cos(2pi k n/64) : sin(2pi k (n-32)/64)
        f16x8 pv;
        int nn = sn & 31;
        #pragma unroll
        for (int j = 0; j < 8; ++j) {
            int kk = ((sk0 + j) * nn) & 63;
            float a = (float)kk * (6.283185307179586f / 64.0f);
            float s, c; __sincosf(a, &s, &c);
            pv[j] = (_Float16)((sn < 32) ? c : s);
        }
        *(f16x8*)&L[OFF_T + widx] = pv;
    }
    __syncthreads();

    const float* xb = x + (size_t)b * N_ * 64;
    float* ob_g = out + (size_t)b * N_ * 64;

    int hbase = (lane >> 5) * 512 + ((lane >> 3) & 3) * 128 + (lane & 7);  // frag offset for d=lane

    // ---------------- stage 1: zc_rms(x) -> xf (A-frag fp16) ----------------
    {
        float gn = g_norm[lane];
        #pragma unroll 5
        for (int c = 0; c < 15; ++c) {
            int row = wave * 15 + c;
            float xv = xb[row * 64 + lane];
            float sx = xv, sxx = xv * xv;
            #pragma unroll
            for (int m = 1; m < 64; m <<= 1) { sx += __shfl_xor(sx, m); sxx += __shfl_xor(sxx, m); }
            float mean = sx * 0.015625f;
            float var  = sxx * 0.015625f - mean * mean;
            float h = (xv - mean) * rsqrtf(var + 1e-8f) * gn;
            float hp = __shfl_xor(h, 1);
            if (!(lane & 1)) {
                f16x2 pk2 = { (_Float16)h, (_Float16)hp };
                *(f16x2*)&L[OFF_XF + (row >> 4) * 1024 + (row & 15) * 8 + hbase] = pk2;
            }
        }
    }
    __syncthreads();

    // ---------------- stage 2: MFMA projections, results held in regs ----------------
    int grp = lane >> 4, li = lane & 15;
    int rbase = wave * 16 + grp * 4;
    {
        const f16x8* hfv = (const f16x8*)(L + OFF_XF);
        f16x8 a0 = hfv[wave * 128 + lane];
        f16x8 a1 = hfv[wave * 128 + 64 + lane];
        f32x4 accT[4];

        // gamma first (frees accT before q/k/v persist)
        mm4(a0, a1, L + OFF_T, lane, accT);
        {
            int gb2 = lane & 48;
            #pragma unroll
            for (int reg = 0; reg < 4; ++reg) {
                float re1 = accT[0][reg], re2 = accT[1][reg];
                float im1 = accT[2][reg], im2 = accT[3][reg];
                float m1 = sqrtf(fmaf(re1, re1, im1 * im1));
                float m2 = sqrtf(fmaf(re2, re2, im2 * im2));
                m1 += __shfl_xor(m1, 1); m2 += __shfl_xor(m2, 1);
                m1 += __shfl_xor(m1, 2); m2 += __shfl_xor(m2, 2);
                float e1 = m1 * 0.25f, e2 = m2 * 0.25f;       // bands li>>2, 4+(li>>2)
                float tot = e1 + e2;
                tot += __shfl_xor(tot, 4); tot += __shfl_xor(tot, 8);
                float rinv = 1.0f / fmaxf(tot, 1e-8f);
                float en1 = e1 * rinv, en2 = e2 * rinv;
                float hs = sb1[li];
                #pragma unroll
                for (int i = 0; i < 4; ++i)
                    hs = fmaf(__shfl(en1, gb2 + (i << 2)), sW1[i * 16 + li], hs);
                #pragma unroll
                for (int i = 0; i < 4; ++i)
                    hs = fmaf(__shfl(en2, gb2 + (i << 2)), sW1[(i + 4) * 16 + li], hs);
                float act = hs / (1.0f + __expf(-hs));        // silu
                float p = act * sW2[li];
                p += __shfl_xor(p, 1); p += __shfl_xor(p, 2);
                p += __shfl_xor(p, 4); p += __shfl_xor(p, 8);
                float raw = 1.0f / (1.0f + __expf(-(p + sb2_s[0])));
                int row = rbase + reg;
                if (li == 0 && row < N_) g_s[row] = fmaf(0.49f, raw, 0.5f);
            }
        }

        f32x4 accq[4], acck[4], accv[4];
        mm4(a0, a1, L + OFF_WQ, lane, accq);
        mm4(a0, a1, L + OFF_WK, lane, acck);
        mm4(a0, a1, L + OFF_WV, lane, accv);

        // l2norm scales (regs/shfl only, pre-barrier)
        {
            f32x4 sq = accq[0]*accq[0] + accq[1]*accq[1] + accq[2]*accq[2] + accq[3]*accq[3];
            f32x4 sk = acck[0]*acck[0] + acck[1]*acck[1] + acck[2]*acck[2] + acck[3]*acck[3];
            #pragma unroll
            for (int reg = 0; reg < 4; ++reg) {
                float qs = sq[reg], ks = sk[reg];
                #pragma unroll
                for (int m = 1; m < 16; m <<= 1) { qs += __shfl_xor(qs, m); ks += __shfl_xor(ks, m); }
                float rq = rsqrtf(qs + 1e-8f), rk = rsqrtf(ks + 1e-8f);
                #pragma unroll
                for (int nt = 0; nt < 4; ++nt) { accq[nt][reg] *= rq; acck[nt][reg] *= rk; }
            }
            #pragma unroll
            for (int nt = 0; nt < 4; ++nt) {
                float bvn = bv_s[nt * 16 + li];
                #pragma unroll
                for (int reg = 0; reg < 4; ++reg) accv[nt][reg] += bvn;
            }
        }
        __syncthreads();   // all waves done reading Wq/Wk/Wv/T/xf

        // writeback q/k/v as fp16 over the dead weight/xf regions
        #pragma unroll
        for (int reg = 0; reg < 4; ++reg) {
            int row = rbase + reg;
            if (row < N_) {
                int base = row * 64 + li;
                #pragma unroll
                for (int nt = 0; nt < 4; ++nt) {
                    L[OFF_QS + base + nt * 16] = (_Float16)accq[nt][reg];
                    L[OFF_KS + base + nt * 16] = (_Float16)acck[nt][reg];
                    L[OFF_VS + base + nt * 16] = (_Float16)accv[nt][reg];
                }
            }
        }
    }
    __syncthreads();

    // ---------------- stage 3: scan, 100% LDS (no global ops in loop) ----------------
    {
        int dlo = lane & 7, g8 = lane >> 3;
        int d = wave * 8 + dlo;
        int co = g8 * 8;
        int dbase = (d >> 5) * 512 + ((d >> 3) & 3) * 128 + (d & 7);  // o_f frag base for col d
        const _Float16* ks = L + OFF_KS;
        const _Float16* qs = L + OFF_QS;
        const _Float16* vs = L + OFF_VS;

        float S[8];
        #pragma unroll
        for (int j = 0; j < 8; ++j) S[j] = 0.f;

        f16x8 kh = *(const f16x8*)&ks[co];
        f16x8 qh = *(const f16x8*)&qs[co];
        _Float16 vh = vs[d];
        float gt = g_s[0];

        for (int t = 0; t < N_; ++t) {
            int tn = (t + 1 < N_) ? (t + 1) : t;
            f16x8 khn = *(const f16x8*)&ks[tn * 64 + co];
            f16x8 qhn = *(const f16x8*)&qs[tn * 64 + co];
            _Float16 vhn = vs[tn * 64 + d];
            float gtn = g_s[tn];

            float p0 = 0.f, p1 = 0.f, p2 = 0.f, p3 = 0.f;
            p0 = fmaf(S[0], (float)kh[0], p0); p1 = fmaf(S[1], (float)kh[1], p1);
            p2 = fmaf(S[2], (float)kh[2], p2); p3 = fmaf(S[3], (float)kh[3], p3);
            p0 = fmaf(S[4], (float)kh[4], p0); p1 = fmaf(S[5], (float)kh[5], p1);
            p2 = fmaf(S[6], (float)kh[6], p2); p3 = fmaf(S[7], (float)kh[7], p3);
            float p = (p0 + p1) + (p2 + p3);
            p += __shfl_xor(p, 8); p += __shfl_xor(p, 16); p += __shfl_xor(p, 32);

            float delta = fminf(fmaxf((float)vh - p, -5.0f), 5.0f);

            float oa = 0.f, ob = 0.f;
#define UPD(j, oo) { float s = fmaf(delta, (float)kh[j], gt * S[j]);           \
                     s = fminf(fmaxf(s, -10.f), 10.f); S[j] = s;               \
                     oo = fmaf(s, (float)qh[j], oo); }
            UPD(0, oa) UPD(1, ob) UPD(2, oa) UPD(3, ob)
            UPD(4, oa) UPD(5, ob) UPD(6, oa) UPD(7, ob)
#undef UPD
            float o = oa + ob;
            o += __shfl_xor(o, 8); o += __shfl_xor(o, 16); o += __shfl_xor(o, 32);
            if (g8 == 0)
                L[OFF_OF + (t >> 4) * 1024 + (t & 15) * 8 + dbase] = (_Float16)o;

            kh = khn; qh = qhn; vh = vhn; gt = gtn;
        }
    }
    __syncthreads();

    // ---------------- stage 4a: zc_rms(o) in place in o_f (A-frag) ----------------
    {
        float gp = g_post[lane];
        #pragma unroll 5
        for (int c = 0; c < 15; ++c) {
            int row = wave * 15 + c;
            int ridx = OFF_OF + (row >> 4) * 1024 + (row & 15) * 8;
            float ov = (float)L[ridx + hbase];
            float sx = ov, sxx = ov * ov;
            #pragma unroll
            for (int m = 1; m < 64; m <<= 1) { sx += __shfl_xor(sx, m); sxx += __shfl_xor(sxx, m); }
            float mean = sx * 0.015625f;
            float var  = sxx * 0.015625f - mean * mean;
            float hn = (ov - mean) * rsqrtf(var + 1e-8f) * gp;
            float hp = __shfl_xor(hn, 1);
            if (!(lane & 1)) {
                f16x2 pk2 = { (_Float16)hn, (_Float16)hp };
                *(f16x2*)&L[ridx + hbase] = pk2;   // same-wave read->write, DS in-order
            }
        }
    }
    __syncthreads();

    // ---------------- stage 4b: out = x + zc_rms(o) @ Wo + bo ----------------
    {
        const f16x8* hfv = (const f16x8*)(L + OFF_OF);
        f16x8 a0 = hfv[wave * 128 + lane];
        f16x8 a1 = hfv[wave * 128 + 64 + lane];
        f32x4 acc[4];
        mm4(a0, a1, L + OFF_WO, lane, acc);
        #pragma unroll
        for (int reg = 0; reg < 4; ++reg) {
            int row = rbase + reg;
            if (row < N_) {
                #pragma unroll
                for (int nt = 0; nt < 4; ++nt) {
                    int idx = row * 64 + nt * 16 + li;
                    ob_g[idx] = acc[nt][reg] + bo_s[nt * 16 + li] + xb[idx];
                }
            }
        }
    }
}

extern "C" void kernel_launch(void* const* d_in, const int* in_sizes, int n_in,
                              void* d_out, int out_size, void* d_ws, size_t ws_size,
                              hipStream_t stream)
{
    const float* x      = (const float*)d_in[0];
    const float* g_norm = (const float*)d_in[1];
    const float* Wq     = (const float*)d_in[2];
    const float* Wk     = (const float*)d_in[3];
    const float* Wv     = (const float*)d_in[4];
    const float* bv     = (const float*)d_in[5];
    const float* Wo     = (const float*)d_in[6];
    const float* bo     = (const float*)d_in[7];
    const float* g_post = (const float*)d_in[8];
    const float* W1     = (const float*)d_in[9];
    const float* b1     = (const float*)d_in[10];
    const float* W2     = (const float*)d_in[11];
    const float* b2     = (const float*)d_in[12];
    float* out = (float*)d_out;

    fused_kdn<<<B_, 512, 0, stream>>>(x, g_norm, Wq, Wk, Wv, bv, Wo, bo, g_post,
                                      W1, b1, W2, b2, out);
}